// Round 11
// baseline (396.435 us; speedup 1.0000x reference)
//
#include <hip/hip_runtime.h>
#include <math.h>

#define HD   64
#define EIN  8
#define SAS  168          // sW1 row stride in u16 (336 B): bank step 20 -> conflict-light
#define W2S  72           // sW2/X1 row stride in u16 (144 B)
#define NORM_INV 0.01f
#define NTH  256          // 4 waves/block
#define NBLK 768          // 3 blocks/CU x 256 CUs
#define NWAVES (NBLK * (NTH / 64))

typedef short bf16x8 __attribute__((ext_vector_type(8)));
typedef float f32x4  __attribute__((ext_vector_type(4)));
typedef float f4v    __attribute__((ext_vector_type(4)));

__device__ __forceinline__ unsigned short f2bf(float f) {
    union { float f; unsigned u; } v; v.f = f;
    unsigned r = v.u + 0x7FFFu + ((v.u >> 16) & 1u);
    return (unsigned short)(r >> 16);
}
__device__ __forceinline__ unsigned pk2(float a, float b) {
    return (unsigned)f2bf(a) | ((unsigned)f2bf(b) << 16);
}
__device__ __forceinline__ float silu_f(float x) {
    return x * __builtin_amdgcn_rcpf(1.0f + __expf(-x));
}

// prep: h -> bf16 table in ws + coord -> out copy
__global__ void prep_h_kernel(const float* __restrict__ h, unsigned short* __restrict__ hbf,
                              int npairs, const float* __restrict__ coord,
                              float* __restrict__ out, int n3) {
    int i = blockIdx.x * blockDim.x + threadIdx.x;
    if (i < npairs) {
        float2 v = reinterpret_cast<const float2*>(h)[i];
        ushort2 o; o.x = f2bf(v.x); o.y = f2bf(v.y);
        reinterpret_cast<ushort2*>(hbf)[i] = o;
    }
    if (i < n3) out[i] = coord[i];
}

__global__ void prep_out_kernel(const float* __restrict__ coord,
                                float* __restrict__ out, int n3) {
    int i = blockIdx.x * blockDim.x + threadIdx.x;
    if (i < n3) out[i] = coord[i];
}

// r10 direct-fragment pipeline + DUAL-GROUP ILP: each wave processes two
// consecutive 16-edge groups per iteration as independent parallel work
// (phase-interleaved), doubling outstanding gathers per wave. This is
// same-iteration ILP, not cross-iteration prefetch -- nothing to sink.
template <bool HB>
__global__ __launch_bounds__(NTH, 3) void egnn_mfma_kernel(
    const float* __restrict__ h,             // fp32 h (when !HB)
    const unsigned short* __restrict__ hbf,  // bf16 h table in ws (when HB)
    const float* __restrict__ coord,
    const int*   __restrict__ eidx,   // [2][E]
    const float* __restrict__ eattr,  // [E][8]
    const float* __restrict__ W1f,    // [136][64] fp32
    const float* __restrict__ W2f,    // [64][64] fp32
    const float* __restrict__ b1,
    const float* __restrict__ b2,
    const float* __restrict__ W3,
    float* __restrict__ out,
    int E_)
{
    __shared__ unsigned short sW1[64 * SAS];      // 21504 B
    __shared__ unsigned short sW2[64 * W2S];      //  9216 B
    __shared__ unsigned short sX1[128 * W2S];     // 18432 B (2 rows per lane)
    __shared__ float sB1[64], sB2[64], sW3[64];   //   768 B

    const int t = threadIdx.x;

    // ---- weights -> LDS (once per block) ----
    for (int i = t; i < 136 * 64; i += NTH) {
        int k = i >> 6, n = i & 63;
        sW1[n * SAS + k] = f2bf(W1f[i]);
    }
    for (int i = t; i < 24 * 64; i += NTH) {      // zero-pad W1 k=136..159
        int n = i / 24, k = 136 + (i - n * 24);
        sW1[n * SAS + k] = 0;
    }
    for (int i = t; i < 64 * 64; i += NTH) {
        int k = i >> 6, n = i & 63;
        sW2[n * W2S + k] = f2bf(W2f[i]);
    }
    if (t < 64) sB1[t] = b1[t];
    else if (t < 128) sB2[t - 64] = b2[t - 64];
    else if (t < 192) sW3[t - 128] = W3[t - 128];
    __syncthreads();                               // the ONLY barrier

    const int w = t >> 6, lane = t & 63;
    const int m = lane & 15, q = lane >> 4;

    unsigned short* x1Row[2];
    x1Row[0] = sX1 + (16 * w + m) * W2S;
    x1Row[1] = sX1 + (64 + 16 * w + m) * W2S;

    const int npairs_g = (((E_ + 15) >> 4) + 1) >> 1;   // pairs of groups
    for (int j = blockIdx.x * (NTH / 64) + w; j < npairs_g; j += NWAVES) {
        const int g2 = j * 2;

        // ---------- per-lane edge indices for both groups ----------
        int e[2], ec[2], row[2], col[2];
#pragma unroll
        for (int u = 0; u < 2; ++u) {
            e[u] = (g2 + u) * 16 + m;
            ec[u] = (e[u] < E_) ? e[u] : (E_ - 1);
            row[u] = eidx[ec[u]];
            col[u] = eidx[(size_t)E_ + ec[u]];
        }

        // coord loads early (latency hidden behind everything below)
        float cr[2] = {0.f, 0.f}, cc[2] = {0.f, 0.f};
#pragma unroll
        for (int u = 0; u < 2; ++u)
            if (q < 3) { cr[u] = coord[row[u] * 3 + q]; cc[u] = coord[col[u] * 3 + q]; }

        // ---------- layer-1 B-fragments: direct 16 B gathers, both groups ----------
        bf16x8 bf[2][5];
#pragma unroll
        for (int u = 0; u < 2; ++u) {
            if (HB) {
                const bf16x8* hr = (const bf16x8*)(hbf + (size_t)row[u] * HD);
                const bf16x8* hc = (const bf16x8*)(hbf + (size_t)col[u] * HD);
                bf[u][0] = hr[q];
                bf[u][1] = hr[4 + q];
                bf[u][2] = hc[q];
                bf[u][3] = hc[4 + q];
            } else {
                const f4v* hr = (const f4v*)(h + (size_t)row[u] * HD);
                const f4v* hc = (const f4v*)(h + (size_t)col[u] * HD);
#pragma unroll
                for (int s = 0; s < 4; ++s) {
                    const f4v* src = (s < 2) ? hr : hc;
                    f4v a = src[(s & 1) * 8 + q * 2];
                    f4v b = src[(s & 1) * 8 + q * 2 + 1];
                    union { bf16x8 v; uint4 uu; } pk;
                    pk.uu.x = pk2(a.x, a.y); pk.uu.y = pk2(a.z, a.w);
                    pk.uu.z = pk2(b.x, b.y); pk.uu.w = pk2(b.z, b.w);
                    bf[u][s] = pk.v;
                }
            }
            union { bf16x8 v; uint4 uu; } pk;
            pk.uu.x = 0; pk.uu.y = 0; pk.uu.z = 0; pk.uu.w = 0;
            if (q == 0) {                       // k = 128..135: edge_attr
                f4v a0 = ((const f4v*)(eattr + (size_t)ec[u] * EIN))[0];
                f4v a1 = ((const f4v*)(eattr + (size_t)ec[u] * EIN))[1];
                pk.uu.x = pk2(a0.x, a0.y); pk.uu.y = pk2(a0.z, a0.w);
                pk.uu.z = pk2(a1.x, a1.y); pk.uu.w = pk2(a1.z, a1.w);
            }
            bf[u][4] = pk.v;                    // q>0 lanes: zeros (W1 pad zero)
        }

        // ---------- layer 1, both groups interleaved ----------
        f32x4 acc1[2][4] = {};
#pragma unroll
        for (int s = 0; s < 5; ++s) {
#pragma unroll
            for (int nt = 0; nt < 4; ++nt) {
                bf16x8 afrag = *(const bf16x8*)(sW1 + (16 * nt + m) * SAS + s * 32 + q * 8);
#pragma unroll
                for (int u = 0; u < 2; ++u)
                    acc1[u][nt] = __builtin_amdgcn_mfma_f32_16x16x32_bf16(afrag, bf[u][s], acc1[u][nt], 0, 0, 0);
            }
        }

        // silu(+b1) -> X1 rows (both groups)
#pragma unroll
        for (int nt = 0; nt < 4; ++nt) {
            float4 bb = *(const float4*)(&sB1[16 * nt + 4 * q]);
#pragma unroll
            for (int u = 0; u < 2; ++u) {
                ushort4 o;
                o.x = f2bf(silu_f(acc1[u][nt][0] + bb.x));
                o.y = f2bf(silu_f(acc1[u][nt][1] + bb.y));
                o.z = f2bf(silu_f(acc1[u][nt][2] + bb.z));
                o.w = f2bf(silu_f(acc1[u][nt][3] + bb.w));
                *((ushort4*)(x1Row[u] + 16 * nt + 4 * q)) = o;
            }
        }

        // ---------- layer 2, both groups ----------
        f32x4 acc2[2][4] = {};
#pragma unroll
        for (int s = 0; s < 2; ++s) {
#pragma unroll
            for (int nt = 0; nt < 4; ++nt) {
                bf16x8 afrag = *(const bf16x8*)(sW2 + (16 * nt + m) * W2S + s * 32 + q * 8);
#pragma unroll
                for (int u = 0; u < 2; ++u) {
                    bf16x8 bfrag = *(const bf16x8*)(x1Row[u] + s * 32 + q * 8);
                    acc2[u][nt] = __builtin_amdgcn_mfma_f32_16x16x32_bf16(afrag, bfrag, acc2[u][nt], 0, 0, 0);
                }
            }
        }

        // ---------- epilogue, both groups ----------
#pragma unroll
        for (int u = 0; u < 2; ++u) {
            float p = 0.f;
#pragma unroll
            for (int nt = 0; nt < 4; ++nt) {
                float4 b2v = *(const float4*)(&sB2[16 * nt + 4 * q]);
                float4 w3v = *(const float4*)(&sW3[16 * nt + 4 * q]);
                p = fmaf(silu_f(acc2[u][nt][0] + b2v.x), w3v.x, p);
                p = fmaf(silu_f(acc2[u][nt][1] + b2v.y), w3v.y, p);
                p = fmaf(silu_f(acc2[u][nt][2] + b2v.z), w3v.z, p);
                p = fmaf(silu_f(acc2[u][nt][3] + b2v.w), w3v.w, p);
            }
            p += __shfl_xor(p, 16);
            p += __shfl_xor(p, 32);

            float cd = cr[u] - cc[u];              // q==3 lanes contribute 0
            float r2 = cd * cd;
            r2 += __shfl_xor(r2, 16);
            r2 += __shfl_xor(r2, 32);
            if (e[u] < E_ && q < 3) {
                float inv = __builtin_amdgcn_rcpf(sqrtf(r2 + 1e-8f) + 1.0f);
                atomicAdd(&out[row[u] * 3 + q], cd * (p * NORM_INV * inv));
            }
        }
    }
}

extern "C" void kernel_launch(void* const* d_in, const int* in_sizes, int n_in,
                              void* d_out, int out_size, void* d_ws, size_t ws_size,
                              hipStream_t stream) {
    const float* h         = (const float*)d_in[0];
    const float* coord     = (const float*)d_in[1];
    const int*   eidx      = (const int*)  d_in[2];
    const float* edge_attr = (const float*)d_in[3];
    const float* W1        = (const float*)d_in[4];
    const float* b1        = (const float*)d_in[5];
    const float* W2        = (const float*)d_in[6];
    const float* b2        = (const float*)d_in[7];
    const float* W3        = (const float*)d_in[8];
    float* out = (float*)d_out;

    int E_ = in_sizes[2] / 2;    // edge_index is [2, E]
    int n3 = out_size;           // N*3
    int nf = in_sizes[0];        // N*HD floats of h

    if (ws_size >= (size_t)nf * 2) {             // bf16 h table (6.4 MB)
        unsigned short* hbf = (unsigned short*)d_ws;
        int npairs = nf / 2;
        int pgrid = (npairs > n3 ? npairs : n3);
        hipLaunchKernelGGL(prep_h_kernel, dim3((pgrid + 255) / 256), dim3(256), 0, stream,
                           h, hbf, npairs, coord, out, n3);
        hipLaunchKernelGGL((egnn_mfma_kernel<true>), dim3(NBLK), dim3(NTH), 0, stream,
                           h, hbf, coord, eidx, edge_attr, W1, W2, b1, b2, W3, out, E_);
    } else {
        hipLaunchKernelGGL(prep_out_kernel, dim3((n3 + 255) / 256), dim3(256), 0, stream,
                           coord, out, n3);
        hipLaunchKernelGGL((egnn_mfma_kernel<false>), dim3(NBLK), dim3(NTH), 0, stream,
                           h, (const unsigned short*)nullptr, coord, eidx, edge_attr,
                           W1, W2, b1, b2, W3, out, E_);
    }
}